// Round 10
// baseline (455.398 us; speedup 1.0000x reference)
//
#include <hip/hip_runtime.h>
#include <math.h>

#define B_  16
#define C_  256
#define S_  1024
#define NH  4
#define DK  64
#define P3  768   // 3*NH*DK
#define ND  256   // NH*DK

typedef unsigned short u16;
typedef unsigned int   u32;
typedef float  f32x4  __attribute__((ext_vector_type(4)));
typedef short  bf16x8 __attribute__((ext_vector_type(8)));

#define MFMA16(a, b, c) __builtin_amdgcn_mfma_f32_16x16x32_bf16(a, b, c, 0, 0, 0)

// fold softmax scale*log2(e) into q at projection time
#define QSCALE 0.1803368801111137f   // 0.125 * 1.44269504

#define WAITVM(N) asm volatile("s_waitcnt vmcnt(" #N ")" ::: "memory")
#define BARRIER() asm volatile("s_barrier" ::: "memory")

#if __has_builtin(__builtin_amdgcn_exp2f)
#define EXP2F(x) __builtin_amdgcn_exp2f(x)
#else
#define EXP2F(x) exp2f(x)
#endif

__device__ __forceinline__ u16 f2bf(float f) {
    union { float f; u32 u; } x; x.f = f;
    u32 r = x.u + 0x7fffu + ((x.u >> 16) & 1u);   // RNE
    return (u16)(r >> 16);
}

__device__ __forceinline__ u32 cvtpk(float lo, float hi) {
    u32 r;
    asm("v_cvt_pk_bf16_f32 %0, %1, %2" : "=v"(r) : "v"(lo), "v"(hi));
    return r;
}

__device__ __forceinline__ void stage16(const u16* g, u16* l) {
    __builtin_amdgcn_global_load_lds(
        (const __attribute__((address_space(1))) void*)g,
        (__attribute__((address_space(3))) void*)l, 16, 0, 0);
}

// Device-wide barrier: monotonic counter, all 512 blocks provably resident
// (80 KB LDS => exactly 2 blocks/CU x 256 CUs = grid size), so the spin
// cannot deadlock. threadfence = agent-scope release/acquire (L2 wb/inv)
// handles cross-XCD visibility.
__device__ __forceinline__ void gbarrier(u32* cnt, u32 target) {
    __syncthreads();
    __threadfence();                       // release: flush this XCD's L2
    if (threadIdx.x == 0) {
        atomicAdd(cnt, 1u);
        u32 v;
        do {
            __builtin_amdgcn_s_sleep(8);
            v = __hip_atomic_load(cnt, __ATOMIC_ACQUIRE, __HIP_MEMORY_SCOPE_AGENT);
        } while (v < target);
    }
    __syncthreads();
    __threadfence();                       // acquire: invalidate stale lines
}

// ---------------------------------------------------------------------------
// MEGA KERNEL: all four phases in one launch, separated by global barriers.
// Phase bodies are the R9 kernels verbatim (each in its own scope).
// ---------------------------------------------------------------------------
__global__ __launch_bounds__(256, 2) void attn_block_mega(
    const float* __restrict__ x, const float* __restrict__ wp,
    const float* __restrict__ bp, const float* __restrict__ wo,
    const float* __restrict__ bo, float* __restrict__ out,
    u16* __restrict__ qo, u16* __restrict__ ko, u16* __restrict__ vo,
    u16* __restrict__ obf, u16* __restrict__ wpT, u16* __restrict__ woT,
    u32* __restrict__ cnt)
{
    __shared__ __align__(16) u16 SM[40960];   // 80 KB -> 2 blocks/CU exactly

    const int tid = threadIdx.x;
    const int w = tid >> 6, lane = tid & 63;
    const int n_ = lane & 15, quad = lane >> 4;
    const int blk = blockIdx.x;

    // ===================== phase 0: weight transposes ======================
    if (blk < 64) {
        const int z  = (blk >= 48);
        const int t_ = z ? (blk - 48) : blk;
        const int cx = z ? (t_ & 3) : (t_ % 12);
        const int cy = z ? (t_ >> 2) : (t_ / 12);
        const int Cc = z ? 256 : 768;
        const float* src = z ? wo : wp;
        u16* dst = z ? woT : wpT;
        const int R = 256;
        const int c0 = cx * 64, r0 = cy * 64;

        float* T = (float*)SM;   // [64][65]
        const int l64 = tid & 63, rr0 = tid >> 6;
        #pragma unroll
        for (int t = 0; t < 16; ++t) {
            int rr = rr0 + t * 4;
            T[rr * 65 + l64] = src[(size_t)(r0 + rr) * Cc + c0 + l64];
        }
        __syncthreads();
        const int rp = tid & 31;
        const int cb = tid >> 5;
        #pragma unroll
        for (int t = 0; t < 8; ++t) {
            int c = cb + t * 8;
            u32 lo = f2bf(T[(2 * rp) * 65 + c]);
            u32 hi = f2bf(T[(2 * rp + 1) * 65 + c]);
            *(u32*)&dst[(size_t)(c0 + c) * R + r0 + 2 * rp] = lo | (hi << 16);
        }
    }

    gbarrier(cnt, 512);

    // ===================== phase 1: fused QKV projection ===================
    {
        const int id  = blk;
        const int nid = (id & 7) * 64 + (id >> 3);
        const int hd  = nid & 3;
        const int g   = nid >> 2;
        const int s0  = (g & 7) * 128;
        const int b   = g >> 3;
        const int bh  = b * NH + hd;

        const int kq8  = tid >> 5;
        const int row4 = tid & 31;
        const float* xb = x + ((size_t)b * C_ + kq8 * 8) * S_ + s0 + row4 * 4;

        int awaddr[4];
        {
            const int kc = kq8 >> 2, quadk = kq8 & 3;
            #pragma unroll
            for (int j = 0; j < 4; ++j) {
                int row = row4 * 4 + j;
                awaddr[j] = ((row >> 4) * 2 + kc) * 512 + quadk * 128 +
                            ((((row & 15) + (row >> 4)) & 15) * 8);
            }
        }

        const u16* brp[3];
        #pragma unroll
        for (int i = 0; i < 3; ++i)
            brp[i] = wpT + (size_t)(hd * 192 + (w * 3 + i) * 16 + n_) * C_ + quad * 8;

        f32x4 acc[2][12];
        #pragma unroll
        for (int am = 0; am < 2; ++am)
            #pragma unroll
            for (int nf = 0; nf < 12; ++nf)
                #pragma unroll
                for (int r = 0; r < 4; ++r) acc[am][nf][r] = 0.f;

        float4 av[8];

        #pragma unroll
        for (int ci = 0; ci < 8; ++ci)
            av[ci] = *(const float4*)(xb + (size_t)ci * S_);
        {
            u16* Bs0 = SM + 8192;
            #pragma unroll
            for (int i = 0; i < 3; ++i) {
                stage16(brp[i],      Bs0 + ((w * 3 + i) * 2 + 0) * 512);
                stage16(brp[i] + 32, Bs0 + ((w * 3 + i) * 2 + 1) * 512);
            }
        }
        #pragma unroll
        for (int j = 0; j < 4; ++j) {
            union { bf16x8 v; u32 u[4]; } pk;
            pk.u[0] = cvtpk(av[0][j], av[1][j]);
            pk.u[1] = cvtpk(av[2][j], av[3][j]);
            pk.u[2] = cvtpk(av[4][j], av[5][j]);
            pk.u[3] = cvtpk(av[6][j], av[7][j]);
            *(bf16x8*)&SM[awaddr[j]] = pk.v;
        }
        __syncthreads();

        #pragma unroll
        for (int p = 0; p < 4; ++p) {
            u16* As_ = SM + (p & 1) * 20480;
            u16* Bs_ = As_ + 8192;
            u16* An  = SM + ((p + 1) & 1) * 20480;
            u16* Bn  = An + 8192;

            if (p < 3) {
                #pragma unroll
                for (int ci = 0; ci < 8; ++ci)
                    av[ci] = *(const float4*)(xb + ((size_t)(p + 1) * 64 + ci) * S_);
                #pragma unroll
                for (int i = 0; i < 3; ++i) {
                    stage16(brp[i] + (p + 1) * 64,      Bn + ((w * 3 + i) * 2 + 0) * 512);
                    stage16(brp[i] + (p + 1) * 64 + 32, Bn + ((w * 3 + i) * 2 + 1) * 512);
                }
            }

            #pragma unroll
            for (int kc = 0; kc < 2; ++kc) {
                bf16x8 af0 = *(const bf16x8*)&As_[((2 * w + 0) * 2 + kc) * 512 +
                                                  quad * 128 + (((n_ + 2 * w + 0) & 15) * 8)];
                bf16x8 af1 = *(const bf16x8*)&As_[((2 * w + 1) * 2 + kc) * 512 +
                                                  quad * 128 + (((n_ + 2 * w + 1) & 15) * 8)];
                #pragma unroll
                for (int nf = 0; nf < 12; ++nf) {
                    bf16x8 bf = *(const bf16x8*)&Bs_[(nf * 2 + kc) * 512 + lane * 8];
                    acc[0][nf] = MFMA16(af0, bf, acc[0][nf]);
                    acc[1][nf] = MFMA16(af1, bf, acc[1][nf]);
                }
            }

            if (p < 3) {
                #pragma unroll
                for (int j = 0; j < 4; ++j) {
                    union { bf16x8 v; u32 u[4]; } pk;
                    pk.u[0] = cvtpk(av[0][j], av[1][j]);
                    pk.u[1] = cvtpk(av[2][j], av[3][j]);
                    pk.u[2] = cvtpk(av[4][j], av[5][j]);
                    pk.u[3] = cvtpk(av[6][j], av[7][j]);
                    *(bf16x8*)&An[awaddr[j]] = pk.v;
                }
            }
            __syncthreads();
        }

        float bias[12];
        #pragma unroll
        for (int nf = 0; nf < 12; ++nf) bias[nf] = bp[hd * 192 + nf * 16 + n_];

        u16* Cq = SM;              // [128][72]
        u16* Ck = SM + 9216;       // [128][72]
        u16* Cv = SM + 18432;      // [64][136]

        #pragma unroll
        for (int am = 0; am < 2; ++am) {
            int row0 = w * 32 + am * 16 + quad * 4;
            #pragma unroll
            for (int nf = 0; nf < 4; ++nf)
                #pragma unroll
                for (int r = 0; r < 4; ++r)
                    Cq[(row0 + r) * 72 + nf * 16 + n_] =
                        f2bf((acc[am][nf][r] + bias[nf]) * QSCALE);
            #pragma unroll
            for (int nf = 4; nf < 8; ++nf)
                #pragma unroll
                for (int r = 0; r < 4; ++r)
                    Ck[(row0 + r) * 72 + (nf - 4) * 16 + n_] =
                        f2bf(acc[am][nf][r] + bias[nf]);
            int colb = w * 32 + am * 16 + quad * 4;
            #pragma unroll
            for (int nf = 8; nf < 12; ++nf)
                #pragma unroll
                for (int r = 0; r < 4; ++r)
                    Cv[((nf - 8) * 16 + n_) * 136 + colb + r] =
                        f2bf(acc[am][nf][r] + bias[nf]);
        }
        __syncthreads();

        #pragma unroll
        for (int t = 0; t < 4; ++t) {
            int ii = tid + t * 256;
            int row = ii >> 3, c8 = (ii & 7) * 8;
            *(bf16x8*)&qo[((size_t)bh * S_ + s0 + row) * DK + c8] =
                *(const bf16x8*)&Cq[row * 72 + c8];
        }
        {
            const int jt0 = s0 >> 6;
            const int nk = lane & 15, qd = lane >> 4;
            #pragma unroll
            for (int fi = 0; fi < 2; ++fi) {
                const int f  = 2 * w + fi;
                const int nb = f >> 1, h = f & 1;
                const int rk = 32 * (nb & 1) + 8 * ((nk >> 2) & 3) +
                               4 * (nb >> 1) + (nk & 3);
                #pragma unroll
                for (int tt = 0; tt < 2; ++tt) {
                    *(bf16x8*)&ko[((size_t)((bh * 16 + jt0 + tt) * 8 + f)) * 512 + lane * 8] =
                        *(const bf16x8*)&Ck[(tt * 64 + rk) * 72 + h * 32 + qd * 8];
                    *(bf16x8*)&vo[((size_t)((bh * 16 + jt0 + tt) * 8 + f)) * 512 + lane * 8] =
                        *(const bf16x8*)&Cv[(nb * 16 + nk) * 136 + tt * 64 + h * 32 + qd * 8];
                }
            }
        }
    }

    gbarrier(cnt, 1024);

    // ===================== phase 2: flash attention ========================
    {
        const int id  = blk;
        const int nid = (id & 7) * 64 + (id >> 3);
        const int i0  = (nid & 7) * 128;
        const int bh  = nid >> 3;
        const int hd  = bh & 3;
        const int b   = bh >> 2;

        bf16x8 qf[2][2];
        #pragma unroll
        for (int am = 0; am < 2; ++am) {
            const u16* qrow = qo + ((size_t)bh * S_ + i0 + w * 32 + am * 16 + n_) * DK;
            qf[am][0] = *(const bf16x8*)&qrow[quad * 8];
            qf[am][1] = *(const bf16x8*)&qrow[32 + quad * 8];
        }

        union { bf16x8 v; u32 u[4]; } ones_;
        #pragma unroll
        for (int i = 0; i < 4; ++i) ones_.u[i] = 0x3F803F80u;
        const bf16x8 onesf = ones_.v;

        const u16* ksrc = ko + (size_t)bh * 16 * 4096 + (2 * w) * 512 + lane * 8;
        const u16* vsrc = vo + (size_t)bh * 16 * 4096 + (2 * w) * 512 + lane * 8;

        f32x4 oacc[2][4];
        f32x4 acc_sum[2];
        #pragma unroll
        for (int am = 0; am < 2; ++am) {
            #pragma unroll
            for (int nd = 0; nd < 4; ++nd)
                #pragma unroll
                for (int r = 0; r < 4; ++r) oacc[am][nd][r] = 0.f;
            #pragma unroll
            for (int r = 0; r < 4; ++r) acc_sum[am][r] = 0.f;
        }

        #pragma unroll
        for (int tt = 0; tt < 2; ++tt) {
            u16* Ks = SM + tt * 8192;
            stage16(ksrc + (size_t)tt * 4096,       Ks + (2 * w + 0) * 512);
            stage16(ksrc + (size_t)tt * 4096 + 512, Ks + (2 * w + 1) * 512);
            stage16(vsrc + (size_t)tt * 4096,       Ks + 4096 + (2 * w + 0) * 512);
            stage16(vsrc + (size_t)tt * 4096 + 512, Ks + 4096 + (2 * w + 1) * 512);
        }

        bf16x8 pa[2][2];

        for (int t = 0; t < 16; ++t) {
            u16* Ks = SM + (t & 3) * 8192;
            u16* Vp = SM + ((t + 3) & 3) * 8192 + 4096;
            if (t < 15) WAITVM(4); else WAITVM(0);
            BARRIER();
            if (t < 14) {
                u16* Kn = SM + ((t + 2) & 3) * 8192;
                stage16(ksrc + (size_t)(t + 2) * 4096,       Kn + (2 * w + 0) * 512);
                stage16(ksrc + (size_t)(t + 2) * 4096 + 512, Kn + (2 * w + 1) * 512);
                stage16(vsrc + (size_t)(t + 2) * 4096,       Kn + 4096 + (2 * w + 0) * 512);
                stage16(vsrc + (size_t)(t + 2) * 4096 + 512, Kn + 4096 + (2 * w + 1) * 512);
            }

            f32x4 sb[2][4];
            __builtin_amdgcn_s_setprio(1);
            #pragma unroll
            for (int nb = 0; nb < 4; ++nb) {
                bf16x8 kf0 = *(const bf16x8*)&Ks[(nb * 2 + 0) * 512 + lane * 8];
                bf16x8 kf1 = *(const bf16x8*)&Ks[(nb * 2 + 1) * 512 + lane * 8];
                #pragma unroll
                for (int am = 0; am < 2; ++am) {
                    f32x4 a; a[0] = a[1] = a[2] = a[3] = 0.f;
                    a = MFMA16(kf0, qf[am][0], a);
                    a = MFMA16(kf1, qf[am][1], a);
                    sb[am][nb] = a;
                }
            }

            if (t > 0) {
                #pragma unroll
                for (int nd = 0; nd < 4; ++nd) {
                    bf16x8 vf0 = *(const bf16x8*)&Vp[(nd * 2 + 0) * 512 + lane * 8];
                    bf16x8 vf1 = *(const bf16x8*)&Vp[(nd * 2 + 1) * 512 + lane * 8];
                    #pragma unroll
                    for (int am = 0; am < 2; ++am) {
                        oacc[am][nd] = MFMA16(vf0, pa[am][0], oacc[am][nd]);
                        oacc[am][nd] = MFMA16(vf1, pa[am][1], oacc[am][nd]);
                    }
                }
                #pragma unroll
                for (int am = 0; am < 2; ++am) {
                    acc_sum[am] = MFMA16(onesf, pa[am][0], acc_sum[am]);
                    acc_sum[am] = MFMA16(onesf, pa[am][1], acc_sum[am]);
                }
            }
            __builtin_amdgcn_s_setprio(0);

            #pragma unroll
            for (int am = 0; am < 2; ++am) {
                float pr[4][4];
                #pragma unroll
                for (int nb = 0; nb < 4; ++nb)
                    #pragma unroll
                    for (int r = 0; r < 4; ++r)
                        pr[nb][r] = EXP2F(sb[am][nb][r]);
                union { bf16x8 v; u32 u[4]; } p0, p1;
                p0.u[0] = cvtpk(pr[0][0], pr[0][1]);
                p0.u[1] = cvtpk(pr[0][2], pr[0][3]);
                p0.u[2] = cvtpk(pr[2][0], pr[2][1]);
                p0.u[3] = cvtpk(pr[2][2], pr[2][3]);
                p1.u[0] = cvtpk(pr[1][0], pr[1][1]);
                p1.u[1] = cvtpk(pr[1][2], pr[1][3]);
                p1.u[2] = cvtpk(pr[3][0], pr[3][1]);
                p1.u[3] = cvtpk(pr[3][2], pr[3][3]);
                pa[am][0] = p0.v;
                pa[am][1] = p1.v;
            }
        }

        {
            u16* Vp = SM + 3 * 8192 + 4096;
            __builtin_amdgcn_s_setprio(1);
            #pragma unroll
            for (int nd = 0; nd < 4; ++nd) {
                bf16x8 vf0 = *(const bf16x8*)&Vp[(nd * 2 + 0) * 512 + lane * 8];
                bf16x8 vf1 = *(const bf16x8*)&Vp[(nd * 2 + 1) * 512 + lane * 8];
                #pragma unroll
                for (int am = 0; am < 2; ++am) {
                    oacc[am][nd] = MFMA16(vf0, pa[am][0], oacc[am][nd]);
                    oacc[am][nd] = MFMA16(vf1, pa[am][1], oacc[am][nd]);
                }
            }
            #pragma unroll
            for (int am = 0; am < 2; ++am) {
                acc_sum[am] = MFMA16(onesf, pa[am][0], acc_sum[am]);
                acc_sum[am] = MFMA16(onesf, pa[am][1], acc_sum[am]);
            }
            __builtin_amdgcn_s_setprio(0);
        }

        const float inv0 = 1.f / acc_sum[0][0];
        const float inv1 = 1.f / acc_sum[1][0];
        float inv[2] = {inv0, inv1};

        __syncthreads();
        u16* eb = SM + w * 2304;   // [32][72]
        #pragma unroll
        for (int am = 0; am < 2; ++am)
            #pragma unroll
            for (int nd = 0; nd < 4; ++nd) {
                uint2 uv;
                uv.x = cvtpk(oacc[am][nd][0] * inv[am], oacc[am][nd][1] * inv[am]);
                uv.y = cvtpk(oacc[am][nd][2] * inv[am], oacc[am][nd][3] * inv[am]);
                *(uint2*)&eb[(am * 16 + n_) * 72 + nd * 16 + quad * 4] = uv;
            }
        __syncthreads();
        #pragma unroll
        for (int t = 0; t < 4; ++t) {
            int ii = lane + t * 64;
            int row = ii >> 3, c8 = (ii & 7) * 8;
            *(bf16x8*)&obf[((size_t)b * S_ + i0 + w * 32 + row) * ND + hd * DK + c8] =
                *(const bf16x8*)&eb[row * 72 + c8];
        }
    }

    gbarrier(cnt, 1536);

    // ===================== phase 3: out projection =========================
    {
        const int id  = blk;
        const int nid = (id & 7) * 64 + (id >> 3);
        const int c0  = (nid & 3) * 64;
        const int g   = nid >> 2;
        const int s0  = (g & 7) * 128;
        const int b   = g >> 3;

        const u16* ar  = woT + (size_t)(c0 + w * 16 + n_) * ND + quad * 8;
        const u16* br0 = obf + ((size_t)b * S_ + s0 + (2 * w + 0) * 16 + n_) * ND + quad * 8;
        const u16* br1 = obf + ((size_t)b * S_ + s0 + (2 * w + 1) * 16 + n_) * ND + quad * 8;

        f32x4 acc[2][4];
        #pragma unroll
        for (int nf = 0; nf < 2; ++nf)
            #pragma unroll
            for (int mb = 0; mb < 4; ++mb)
                #pragma unroll
                for (int r = 0; r < 4; ++r) acc[nf][mb][r] = 0.f;

        {
            u16* Bs_ = SM;
            u16* As_ = SM + 8192;
            stage16(br0,      Bs_ + (4 * w + 0) * 512);
            stage16(br0 + 32, Bs_ + (4 * w + 1) * 512);
            stage16(br1,      Bs_ + (4 * w + 2) * 512);
            stage16(br1 + 32, Bs_ + (4 * w + 3) * 512);
            stage16(ar,       As_ + (2 * w + 0) * 512);
            stage16(ar + 32,  As_ + (2 * w + 1) * 512);
        }

        #pragma unroll
        for (int p = 0; p < 4; ++p) {
            u16* Bs_ = SM + (p & 1) * 12288;
            u16* As_ = Bs_ + 8192;
            if (p < 3) {
                const int pk = (p + 1) * 64;
                u16* Bn = SM + ((p + 1) & 1) * 12288;
                u16* An = Bn + 8192;
                stage16(br0 + pk,      Bn + (4 * w + 0) * 512);
                stage16(br0 + pk + 32, Bn + (4 * w + 1) * 512);
                stage16(br1 + pk,      Bn + (4 * w + 2) * 512);
                stage16(br1 + pk + 32, Bn + (4 * w + 3) * 512);
                stage16(ar  + pk,      An + (2 * w + 0) * 512);
                stage16(ar  + pk + 32, An + (2 * w + 1) * 512);
                WAITVM(6);
            } else {
                WAITVM(0);
            }
            BARRIER();
            #pragma unroll
            for (int kc = 0; kc < 2; ++kc) {
                bf16x8 bf0 = *(const bf16x8*)&Bs_[((2 * w + 0) * 2 + kc) * 512 + lane * 8];
                bf16x8 bf1 = *(const bf16x8*)&Bs_[((2 * w + 1) * 2 + kc) * 512 + lane * 8];
                #pragma unroll
                for (int mb = 0; mb < 4; ++mb) {
                    bf16x8 af = *(const bf16x8*)&As_[(mb * 2 + kc) * 512 + lane * 8];
                    acc[0][mb] = MFMA16(af, bf0, acc[0][mb]);
                    acc[1][mb] = MFMA16(af, bf1, acc[1][mb]);
                }
            }
            if (p < 3) BARRIER();
        }

        __syncthreads();
        float* Cf = (float*)SM;    // [64][140] fp32
        #pragma unroll
        for (int mb = 0; mb < 4; ++mb)
            #pragma unroll
            for (int r = 0; r < 4; ++r) {
                int crow = mb * 16 + quad * 4 + r;
                float bias = bo[c0 + crow];
                #pragma unroll
                for (int nf = 0; nf < 2; ++nf)
                    Cf[crow * 140 + w * 32 + nf * 16 + n_] = acc[nf][mb][r] + bias;
            }
        __syncthreads();
        #pragma unroll
        for (int cr = 0; cr < 8; ++cr) {
            int row = w * 16 + cr * 2 + (lane >> 5);
            int s4  = (lane & 31) * 4;
            float4 v = *(const float4*)&Cf[row * 140 + s4];
            size_t gi = ((size_t)b * C_ + c0 + row) * S_ + s0 + s4;
            float4 xv = *(const float4*)&x[gi];
            float4 o;
            o.x = v.x + xv.x; o.y = v.y + xv.y;
            o.z = v.z + xv.z; o.w = v.w + xv.w;
            *(float4*)&out[gi] = o;
        }
    }
}

// ---------------------------------------------------------------------------
extern "C" void kernel_launch(void* const* d_in, const int* in_sizes, int n_in,
                              void* d_out, int out_size, void* d_ws, size_t ws_size,
                              hipStream_t stream) {
    const float* x  = (const float*)d_in[0];
    const float* wp = (const float*)d_in[1];
    const float* bp = (const float*)d_in[2];
    const float* wo = (const float*)d_in[3];
    const float* bo = (const float*)d_in[4];
    float* out = (float*)d_out;

    const size_t QKV_E = (size_t)B_ * NH * S_ * DK;   // 4 Mi
    u16* q   = (u16*)d_ws;
    u16* kk  = q   + QKV_E;
    u16* vtp = kk  + QKV_E;
    u16* obf = vtp + QKV_E;                            // B*S*ND
    u16* wpT = obf + (size_t)B_ * S_ * ND;             // P3*C
    u16* woT = wpT + (size_t)P3 * C_;                  // C*ND
    u32* cnt = (u32*)(woT + (size_t)C_ * ND);          // barrier counter

    hipMemsetAsync(cnt, 0, 64, stream);
    attn_block_mega<<<dim3(512, 1, 1), 256, 0, stream>>>(
        x, wp, bp, wo, bo, out, q, kk, vtp, obf, wpT, woT, cnt);
}

// Round 12
// 438.943 us; speedup vs baseline: 1.0375x; 1.0375x over previous
//
#include <hip/hip_runtime.h>
#include <math.h>

#define B_  16
#define C_  256
#define S_  1024
#define NH  4
#define DK  64
#define P3  768   // 3*NH*DK
#define ND  256   // NH*DK

typedef unsigned short u16;
typedef unsigned int   u32;
typedef float  f32x4  __attribute__((ext_vector_type(4)));
typedef short  bf16x8 __attribute__((ext_vector_type(8)));

#define MFMA16(a, b, c) __builtin_amdgcn_mfma_f32_16x16x32_bf16(a, b, c, 0, 0, 0)

// fold softmax scale*log2(e) into q at projection time
#define QSCALE 0.1803368801111137f   // 0.125 * 1.44269504

#define WAITVM(N) asm volatile("s_waitcnt vmcnt(" #N ")" ::: "memory")
#define BARRIER() asm volatile("s_barrier" ::: "memory")

#if __has_builtin(__builtin_amdgcn_exp2f)
#define EXP2F(x) __builtin_amdgcn_exp2f(x)
#else
#define EXP2F(x) exp2f(x)
#endif

__device__ __forceinline__ u16 f2bf(float f) {
    union { float f; u32 u; } x; x.f = f;
    u32 r = x.u + 0x7fffu + ((x.u >> 16) & 1u);   // RNE
    return (u16)(r >> 16);
}

__device__ __forceinline__ u32 cvtpk(float lo, float hi) {
    u32 r;
    asm("v_cvt_pk_bf16_f32 %0, %1, %2" : "=v"(r) : "v"(lo), "v"(hi));
    return r;
}

__device__ __forceinline__ void stage16(const u16* g, u16* l) {
    __builtin_amdgcn_global_load_lds(
        (const __attribute__((address_space(1))) void*)g,
        (__attribute__((address_space(3))) void*)l, 16, 0, 0);
}

// Device-wide barrier, RMW polling.
// R10 post-mortem: ACQUIRE poll emits a cache-invalidate per iteration ->
// chip-wide cache poison (417us, 2.7% util). R11 post-mortem: RELAXED
// *load* may be serviced from the polling XCD's own non-coherent L2 ->
// stale counter -> infinite spin -> hang. Fix: poll with a RELAXED atomic
// RMW (fetch_add 0) — RMWs always execute at the coherence point (MALL),
// so they observe remote arrivals without any cache invalidation.
// One release fence before arrive, one acquire fence after exit (the
// required cross-XCD wb/inv, paid ONCE per block per phase).
// All 512 blocks provably resident (80 KB LDS => 2 blocks/CU x 256 CU),
// so the spin cannot deadlock on residency.
__device__ __forceinline__ void gbarrier(u32* cnt, u32 target) {
    __syncthreads();
    __threadfence();                       // release: L2 writeback once
    if (threadIdx.x == 0) {
        __hip_atomic_fetch_add(cnt, 1u, __ATOMIC_RELAXED, __HIP_MEMORY_SCOPE_AGENT);
        u32 v;
        do {
            __builtin_amdgcn_s_sleep(32);  // ~0.85 us quantum
            v = __hip_atomic_fetch_add(cnt, 0u, __ATOMIC_RELAXED,
                                       __HIP_MEMORY_SCOPE_AGENT);
        } while (v < target);
    }
    __syncthreads();
    __threadfence();                       // acquire: invalidate stale lines once
}

// ---------------------------------------------------------------------------
// MEGA KERNEL: all four phases in one launch, separated by global barriers.
// Phase bodies are the R9 kernels verbatim (numerics verified in R10's run).
// ---------------------------------------------------------------------------
__global__ __launch_bounds__(256, 2) void attn_block_mega(
    const float* __restrict__ x, const float* __restrict__ wp,
    const float* __restrict__ bp, const float* __restrict__ wo,
    const float* __restrict__ bo, float* __restrict__ out,
    u16* __restrict__ qo, u16* __restrict__ ko, u16* __restrict__ vo,
    u16* __restrict__ obf, u16* __restrict__ wpT, u16* __restrict__ woT,
    u32* __restrict__ cnt)
{
    __shared__ __align__(16) u16 SM[40960];   // 80 KB -> 2 blocks/CU exactly

    const int tid = threadIdx.x;
    const int w = tid >> 6, lane = tid & 63;
    const int n_ = lane & 15, quad = lane >> 4;
    const int blk = blockIdx.x;

    // ===================== phase 0: weight transposes ======================
    if (blk < 64) {
        const int z  = (blk >= 48);
        const int t_ = z ? (blk - 48) : blk;
        const int cx = z ? (t_ & 3) : (t_ % 12);
        const int cy = z ? (t_ >> 2) : (t_ / 12);
        const int Cc = z ? 256 : 768;
        const float* src = z ? wo : wp;
        u16* dst = z ? woT : wpT;
        const int R = 256;
        const int c0 = cx * 64, r0 = cy * 64;

        float* T = (float*)SM;   // [64][65]
        const int l64 = tid & 63, rr0 = tid >> 6;
        #pragma unroll
        for (int t = 0; t < 16; ++t) {
            int rr = rr0 + t * 4;
            T[rr * 65 + l64] = src[(size_t)(r0 + rr) * Cc + c0 + l64];
        }
        __syncthreads();
        const int rp = tid & 31;
        const int cb = tid >> 5;
        #pragma unroll
        for (int t = 0; t < 8; ++t) {
            int c = cb + t * 8;
            u32 lo = f2bf(T[(2 * rp) * 65 + c]);
            u32 hi = f2bf(T[(2 * rp + 1) * 65 + c]);
            *(u32*)&dst[(size_t)(c0 + c) * R + r0 + 2 * rp] = lo | (hi << 16);
        }
    }

    gbarrier(cnt, 512);

    // ===================== phase 1: fused QKV projection ===================
    {
        const int id  = blk;
        const int nid = (id & 7) * 64 + (id >> 3);
        const int hd  = nid & 3;
        const int g   = nid >> 2;
        const int s0  = (g & 7) * 128;
        const int b   = g >> 3;
        const int bh  = b * NH + hd;

        const int kq8  = tid >> 5;
        const int row4 = tid & 31;
        const float* xb = x + ((size_t)b * C_ + kq8 * 8) * S_ + s0 + row4 * 4;

        int awaddr[4];
        {
            const int kc = kq8 >> 2, quadk = kq8 & 3;
            #pragma unroll
            for (int j = 0; j < 4; ++j) {
                int row = row4 * 4 + j;
                awaddr[j] = ((row >> 4) * 2 + kc) * 512 + quadk * 128 +
                            ((((row & 15) + (row >> 4)) & 15) * 8);
            }
        }

        const u16* brp[3];
        #pragma unroll
        for (int i = 0; i < 3; ++i)
            brp[i] = wpT + (size_t)(hd * 192 + (w * 3 + i) * 16 + n_) * C_ + quad * 8;

        f32x4 acc[2][12];
        #pragma unroll
        for (int am = 0; am < 2; ++am)
            #pragma unroll
            for (int nf = 0; nf < 12; ++nf)
                #pragma unroll
                for (int r = 0; r < 4; ++r) acc[am][nf][r] = 0.f;

        float4 av[8];

        #pragma unroll
        for (int ci = 0; ci < 8; ++ci)
            av[ci] = *(const float4*)(xb + (size_t)ci * S_);
        {
            u16* Bs0 = SM + 8192;
            #pragma unroll
            for (int i = 0; i < 3; ++i) {
                stage16(brp[i],      Bs0 + ((w * 3 + i) * 2 + 0) * 512);
                stage16(brp[i] + 32, Bs0 + ((w * 3 + i) * 2 + 1) * 512);
            }
        }
        #pragma unroll
        for (int j = 0; j < 4; ++j) {
            union { bf16x8 v; u32 u[4]; } pk;
            pk.u[0] = cvtpk(av[0][j], av[1][j]);
            pk.u[1] = cvtpk(av[2][j], av[3][j]);
            pk.u[2] = cvtpk(av[4][j], av[5][j]);
            pk.u[3] = cvtpk(av[6][j], av[7][j]);
            *(bf16x8*)&SM[awaddr[j]] = pk.v;
        }
        __syncthreads();

        #pragma unroll
        for (int p = 0; p < 4; ++p) {
            u16* As_ = SM + (p & 1) * 20480;
            u16* Bs_ = As_ + 8192;
            u16* An  = SM + ((p + 1) & 1) * 20480;
            u16* Bn  = An + 8192;

            if (p < 3) {
                #pragma unroll
                for (int ci = 0; ci < 8; ++ci)
                    av[ci] = *(const float4*)(xb + ((size_t)(p + 1) * 64 + ci) * S_);
                #pragma unroll
                for (int i = 0; i < 3; ++i) {
                    stage16(brp[i] + (p + 1) * 64,      Bn + ((w * 3 + i) * 2 + 0) * 512);
                    stage16(brp[i] + (p + 1) * 64 + 32, Bn + ((w * 3 + i) * 2 + 1) * 512);
                }
            }

            #pragma unroll
            for (int kc = 0; kc < 2; ++kc) {
                bf16x8 af0 = *(const bf16x8*)&As_[((2 * w + 0) * 2 + kc) * 512 +
                                                  quad * 128 + (((n_ + 2 * w + 0) & 15) * 8)];
                bf16x8 af1 = *(const bf16x8*)&As_[((2 * w + 1) * 2 + kc) * 512 +
                                                  quad * 128 + (((n_ + 2 * w + 1) & 15) * 8)];
                #pragma unroll
                for (int nf = 0; nf < 12; ++nf) {
                    bf16x8 bf = *(const bf16x8*)&Bs_[(nf * 2 + kc) * 512 + lane * 8];
                    acc[0][nf] = MFMA16(af0, bf, acc[0][nf]);
                    acc[1][nf] = MFMA16(af1, bf, acc[1][nf]);
                }
            }

            if (p < 3) {
                #pragma unroll
                for (int j = 0; j < 4; ++j) {
                    union { bf16x8 v; u32 u[4]; } pk;
                    pk.u[0] = cvtpk(av[0][j], av[1][j]);
                    pk.u[1] = cvtpk(av[2][j], av[3][j]);
                    pk.u[2] = cvtpk(av[4][j], av[5][j]);
                    pk.u[3] = cvtpk(av[6][j], av[7][j]);
                    *(bf16x8*)&An[awaddr[j]] = pk.v;
                }
            }
            __syncthreads();
        }

        float bias[12];
        #pragma unroll
        for (int nf = 0; nf < 12; ++nf) bias[nf] = bp[hd * 192 + nf * 16 + n_];

        u16* Cq = SM;              // [128][72]
        u16* Ck = SM + 9216;       // [128][72]
        u16* Cv = SM + 18432;      // [64][136]

        #pragma unroll
        for (int am = 0; am < 2; ++am) {
            int row0 = w * 32 + am * 16 + quad * 4;
            #pragma unroll
            for (int nf = 0; nf < 4; ++nf)
                #pragma unroll
                for (int r = 0; r < 4; ++r)
                    Cq[(row0 + r) * 72 + nf * 16 + n_] =
                        f2bf((acc[am][nf][r] + bias[nf]) * QSCALE);
            #pragma unroll
            for (int nf = 4; nf < 8; ++nf)
                #pragma unroll
                for (int r = 0; r < 4; ++r)
                    Ck[(row0 + r) * 72 + (nf - 4) * 16 + n_] =
                        f2bf(acc[am][nf][r] + bias[nf]);
            int colb = w * 32 + am * 16 + quad * 4;
            #pragma unroll
            for (int nf = 8; nf < 12; ++nf)
                #pragma unroll
                for (int r = 0; r < 4; ++r)
                    Cv[((nf - 8) * 16 + n_) * 136 + colb + r] =
                        f2bf(acc[am][nf][r] + bias[nf]);
        }
        __syncthreads();

        #pragma unroll
        for (int t = 0; t < 4; ++t) {
            int ii = tid + t * 256;
            int row = ii >> 3, c8 = (ii & 7) * 8;
            *(bf16x8*)&qo[((size_t)bh * S_ + s0 + row) * DK + c8] =
                *(const bf16x8*)&Cq[row * 72 + c8];
        }
        {
            const int jt0 = s0 >> 6;
            const int nk = lane & 15, qd = lane >> 4;
            #pragma unroll
            for (int fi = 0; fi < 2; ++fi) {
                const int f  = 2 * w + fi;
                const int nb = f >> 1, h = f & 1;
                const int rk = 32 * (nb & 1) + 8 * ((nk >> 2) & 3) +
                               4 * (nb >> 1) + (nk & 3);
                #pragma unroll
                for (int tt = 0; tt < 2; ++tt) {
                    *(bf16x8*)&ko[((size_t)((bh * 16 + jt0 + tt) * 8 + f)) * 512 + lane * 8] =
                        *(const bf16x8*)&Ck[(tt * 64 + rk) * 72 + h * 32 + qd * 8];
                    *(bf16x8*)&vo[((size_t)((bh * 16 + jt0 + tt) * 8 + f)) * 512 + lane * 8] =
                        *(const bf16x8*)&Cv[(nb * 16 + nk) * 136 + tt * 64 + h * 32 + qd * 8];
                }
            }
        }
    }

    gbarrier(cnt, 1024);

    // ===================== phase 2: flash attention ========================
    {
        const int id  = blk;
        const int nid = (id & 7) * 64 + (id >> 3);
        const int i0  = (nid & 7) * 128;
        const int bh  = nid >> 3;
        const int hd  = bh & 3;
        const int b   = bh >> 2;

        bf16x8 qf[2][2];
        #pragma unroll
        for (int am = 0; am < 2; ++am) {
            const u16* qrow = qo + ((size_t)bh * S_ + i0 + w * 32 + am * 16 + n_) * DK;
            qf[am][0] = *(const bf16x8*)&qrow[quad * 8];
            qf[am][1] = *(const bf16x8*)&qrow[32 + quad * 8];
        }

        union { bf16x8 v; u32 u[4]; } ones_;
        #pragma unroll
        for (int i = 0; i < 4; ++i) ones_.u[i] = 0x3F803F80u;
        const bf16x8 onesf = ones_.v;

        const u16* ksrc = ko + (size_t)bh * 16 * 4096 + (2 * w) * 512 + lane * 8;
        const u16* vsrc = vo + (size_t)bh * 16 * 4096 + (2 * w) * 512 + lane * 8;

        f32x4 oacc[2][4];
        f32x4 acc_sum[2];
        #pragma unroll
        for (int am = 0; am < 2; ++am) {
            #pragma unroll
            for (int nd = 0; nd < 4; ++nd)
                #pragma unroll
                for (int r = 0; r < 4; ++r) oacc[am][nd][r] = 0.f;
            #pragma unroll
            for (int r = 0; r < 4; ++r) acc_sum[am][r] = 0.f;
        }

        #pragma unroll
        for (int tt = 0; tt < 2; ++tt) {
            u16* Ks = SM + tt * 8192;
            stage16(ksrc + (size_t)tt * 4096,       Ks + (2 * w + 0) * 512);
            stage16(ksrc + (size_t)tt * 4096 + 512, Ks + (2 * w + 1) * 512);
            stage16(vsrc + (size_t)tt * 4096,       Ks + 4096 + (2 * w + 0) * 512);
            stage16(vsrc + (size_t)tt * 4096 + 512, Ks + 4096 + (2 * w + 1) * 512);
        }

        bf16x8 pa[2][2];

        for (int t = 0; t < 16; ++t) {
            u16* Ks = SM + (t & 3) * 8192;
            u16* Vp = SM + ((t + 3) & 3) * 8192 + 4096;
            if (t < 15) WAITVM(4); else WAITVM(0);
            BARRIER();
            if (t < 14) {
                u16* Kn = SM + ((t + 2) & 3) * 8192;
                stage16(ksrc + (size_t)(t + 2) * 4096,       Kn + (2 * w + 0) * 512);
                stage16(ksrc + (size_t)(t + 2) * 4096 + 512, Kn + (2 * w + 1) * 512);
                stage16(vsrc + (size_t)(t + 2) * 4096,       Kn + 4096 + (2 * w + 0) * 512);
                stage16(vsrc + (size_t)(t + 2) * 4096 + 512, Kn + 4096 + (2 * w + 1) * 512);
            }

            f32x4 sb[2][4];
            __builtin_amdgcn_s_setprio(1);
            #pragma unroll
            for (int nb = 0; nb < 4; ++nb) {
                bf16x8 kf0 = *(const bf16x8*)&Ks[(nb * 2 + 0) * 512 + lane * 8];
                bf16x8 kf1 = *(const bf16x8*)&Ks[(nb * 2 + 1) * 512 + lane * 8];
                #pragma unroll
                for (int am = 0; am < 2; ++am) {
                    f32x4 a; a[0] = a[1] = a[2] = a[3] = 0.f;
                    a = MFMA16(kf0, qf[am][0], a);
                    a = MFMA16(kf1, qf[am][1], a);
                    sb[am][nb] = a;
                }
            }

            if (t > 0) {
                #pragma unroll
                for (int nd = 0; nd < 4; ++nd) {
                    bf16x8 vf0 = *(const bf16x8*)&Vp[(nd * 2 + 0) * 512 + lane * 8];
                    bf16x8 vf1 = *(const bf16x8*)&Vp[(nd * 2 + 1) * 512 + lane * 8];
                    #pragma unroll
                    for (int am = 0; am < 2; ++am) {
                        oacc[am][nd] = MFMA16(vf0, pa[am][0], oacc[am][nd]);
                        oacc[am][nd] = MFMA16(vf1, pa[am][1], oacc[am][nd]);
                    }
                }
                #pragma unroll
                for (int am = 0; am < 2; ++am) {
                    acc_sum[am] = MFMA16(onesf, pa[am][0], acc_sum[am]);
                    acc_sum[am] = MFMA16(onesf, pa[am][1], acc_sum[am]);
                }
            }
            __builtin_amdgcn_s_setprio(0);

            #pragma unroll
            for (int am = 0; am < 2; ++am) {
                float pr[4][4];
                #pragma unroll
                for (int nb = 0; nb < 4; ++nb)
                    #pragma unroll
                    for (int r = 0; r < 4; ++r)
                        pr[nb][r] = EXP2F(sb[am][nb][r]);
                union { bf16x8 v; u32 u[4]; } p0, p1;
                p0.u[0] = cvtpk(pr[0][0], pr[0][1]);
                p0.u[1] = cvtpk(pr[0][2], pr[0][3]);
                p0.u[2] = cvtpk(pr[2][0], pr[2][1]);
                p0.u[3] = cvtpk(pr[2][2], pr[2][3]);
                p1.u[0] = cvtpk(pr[1][0], pr[1][1]);
                p1.u[1] = cvtpk(pr[1][2], pr[1][3]);
                p1.u[2] = cvtpk(pr[3][0], pr[3][1]);
                p1.u[3] = cvtpk(pr[3][2], pr[3][3]);
                pa[am][0] = p0.v;
                pa[am][1] = p1.v;
            }
        }

        {
            u16* Vp = SM + 3 * 8192 + 4096;
            __builtin_amdgcn_s_setprio(1);
            #pragma unroll
            for (int nd = 0; nd < 4; ++nd) {
                bf16x8 vf0 = *(const bf16x8*)&Vp[(nd * 2 + 0) * 512 + lane * 8];
                bf16x8 vf1 = *(const bf16x8*)&Vp[(nd * 2 + 1) * 512 + lane * 8];
                #pragma unroll
                for (int am = 0; am < 2; ++am) {
                    oacc[am][nd] = MFMA16(vf0, pa[am][0], oacc[am][nd]);
                    oacc[am][nd] = MFMA16(vf1, pa[am][1], oacc[am][nd]);
                }
            }
            #pragma unroll
            for (int am = 0; am < 2; ++am) {
                acc_sum[am] = MFMA16(onesf, pa[am][0], acc_sum[am]);
                acc_sum[am] = MFMA16(onesf, pa[am][1], acc_sum[am]);
            }
            __builtin_amdgcn_s_setprio(0);
        }

        const float inv0 = 1.f / acc_sum[0][0];
        const float inv1 = 1.f / acc_sum[1][0];
        float inv[2] = {inv0, inv1};

        __syncthreads();
        u16* eb = SM + w * 2304;   // [32][72]
        #pragma unroll
        for (int am = 0; am < 2; ++am)
            #pragma unroll
            for (int nd = 0; nd < 4; ++nd) {
                uint2 uv;
                uv.x = cvtpk(oacc[am][nd][0] * inv[am], oacc[am][nd][1] * inv[am]);
                uv.y = cvtpk(oacc[am][nd][2] * inv[am], oacc[am][nd][3] * inv[am]);
                *(uint2*)&eb[(am * 16 + n_) * 72 + nd * 16 + quad * 4] = uv;
            }
        __syncthreads();
        #pragma unroll
        for (int t = 0; t < 4; ++t) {
            int ii = lane + t * 64;
            int row = ii >> 3, c8 = (ii & 7) * 8;
            *(bf16x8*)&obf[((size_t)b * S_ + i0 + w * 32 + row) * ND + hd * DK + c8] =
                *(const bf16x8*)&eb[row * 72 + c8];
        }
    }

    gbarrier(cnt, 1536);

    // ===================== phase 3: out projection =========================
    {
        const int id  = blk;
        const int nid = (id & 7) * 64 + (id >> 3);
        const int c0  = (nid & 3) * 64;
        const int g   = nid >> 2;
        const int s0  = (g & 7) * 128;
        const int b   = g >> 3;

        const u16* ar  = woT + (size_t)(c0 + w * 16 + n_) * ND + quad * 8;
        const u16* br0 = obf + ((size_t)b * S_ + s0 + (2 * w + 0) * 16 + n_) * ND + quad * 8;
        const u16* br1 = obf + ((size_t)b * S_ + s0 + (2 * w + 1) * 16 + n_) * ND + quad * 8;

        f32x4 acc[2][4];
        #pragma unroll
        for (int nf = 0; nf < 2; ++nf)
            #pragma unroll
            for (int mb = 0; mb < 4; ++mb)
                #pragma unroll
                for (int r = 0; r < 4; ++r) acc[nf][mb][r] = 0.f;

        {
            u16* Bs_ = SM;
            u16* As_ = SM + 8192;
            stage16(br0,      Bs_ + (4 * w + 0) * 512);
            stage16(br0 + 32, Bs_ + (4 * w + 1) * 512);
            stage16(br1,      Bs_ + (4 * w + 2) * 512);
            stage16(br1 + 32, Bs_ + (4 * w + 3) * 512);
            stage16(ar,       As_ + (2 * w + 0) * 512);
            stage16(ar + 32,  As_ + (2 * w + 1) * 512);
        }

        #pragma unroll
        for (int p = 0; p < 4; ++p) {
            u16* Bs_ = SM + (p & 1) * 12288;
            u16* As_ = Bs_ + 8192;
            if (p < 3) {
                const int pk = (p + 1) * 64;
                u16* Bn = SM + ((p + 1) & 1) * 12288;
                u16* An = Bn + 8192;
                stage16(br0 + pk,      Bn + (4 * w + 0) * 512);
                stage16(br0 + pk + 32, Bn + (4 * w + 1) * 512);
                stage16(br1 + pk,      Bn + (4 * w + 2) * 512);
                stage16(br1 + pk + 32, Bn + (4 * w + 3) * 512);
                stage16(ar  + pk,      An + (2 * w + 0) * 512);
                stage16(ar  + pk + 32, An + (2 * w + 1) * 512);
                WAITVM(6);
            } else {
                WAITVM(0);
            }
            BARRIER();
            #pragma unroll
            for (int kc = 0; kc < 2; ++kc) {
                bf16x8 bf0 = *(const bf16x8*)&Bs_[((2 * w + 0) * 2 + kc) * 512 + lane * 8];
                bf16x8 bf1 = *(const bf16x8*)&Bs_[((2 * w + 1) * 2 + kc) * 512 + lane * 8];
                #pragma unroll
                for (int mb = 0; mb < 4; ++mb) {
                    bf16x8 af = *(const bf16x8*)&As_[(mb * 2 + kc) * 512 + lane * 8];
                    acc[0][mb] = MFMA16(af, bf0, acc[0][mb]);
                    acc[1][mb] = MFMA16(af, bf1, acc[1][mb]);
                }
            }
            if (p < 3) BARRIER();
        }

        __syncthreads();
        float* Cf = (float*)SM;    // [64][140] fp32
        #pragma unroll
        for (int mb = 0; mb < 4; ++mb)
            #pragma unroll
            for (int r = 0; r < 4; ++r) {
                int crow = mb * 16 + quad * 4 + r;
                float bias = bo[c0 + crow];
                #pragma unroll
                for (int nf = 0; nf < 2; ++nf)
                    Cf[crow * 140 + w * 32 + nf * 16 + n_] = acc[nf][mb][r] + bias;
            }
        __syncthreads();
        #pragma unroll
        for (int cr = 0; cr < 8; ++cr) {
            int row = w * 16 + cr * 2 + (lane >> 5);
            int s4  = (lane & 31) * 4;
            float4 v = *(const float4*)&Cf[row * 140 + s4];
            size_t gi = ((size_t)b * C_ + c0 + row) * S_ + s0 + s4;
            float4 xv = *(const float4*)&x[gi];
            float4 o;
            o.x = v.x + xv.x; o.y = v.y + xv.y;
            o.z = v.z + xv.z; o.w = v.w + xv.w;
            *(float4*)&out[gi] = o;
        }
    }
}

// ---------------------------------------------------------------------------
extern "C" void kernel_launch(void* const* d_in, const int* in_sizes, int n_in,
                              void* d_out, int out_size, void* d_ws, size_t ws_size,
                              hipStream_t stream) {
    const float* x  = (const float*)d_in[0];
    const float* wp = (const float*)d_in[1];
    const float* bp = (const float*)d_in[2];
    const float* wo = (const float*)d_in[3];
    const float* bo = (const float*)d_in[4];
    float* out = (float*)d_out;

    const size_t QKV_E = (size_t)B_ * NH * S_ * DK;   // 4 Mi
    u16* q   = (u16*)d_ws;
    u16* kk  = q   + QKV_E;
    u16* vtp = kk  + QKV_E;
    u16* obf = vtp + QKV_E;                            // B*S*ND
    u16* wpT = obf + (size_t)B_ * S_ * ND;             // P3*C
    u16* woT = wpT + (size_t)P3 * C_;                  // C*ND
    u32* cnt = (u32*)(woT + (size_t)C_ * ND);          // barrier counter

    hipMemsetAsync(cnt, 0, 64, stream);
    attn_block_mega<<<dim3(512, 1, 1), 256, 0, stream>>>(
        x, wp, bp, wo, bo, out, q, kk, vtp, obf, wpT, woT, cnt);
}

// Round 13
// 120.659 us; speedup vs baseline: 3.7743x; 3.6379x over previous
//
#include <hip/hip_runtime.h>
#include <math.h>

#define B_  16
#define C_  256
#define S_  1024
#define NH  4
#define DK  64
#define P3  768   // 3*NH*DK
#define ND  256   // NH*DK

typedef unsigned short u16;
typedef unsigned int   u32;
typedef float  f32x4  __attribute__((ext_vector_type(4)));
typedef short  bf16x8 __attribute__((ext_vector_type(8)));

#define MFMA16(a, b, c) __builtin_amdgcn_mfma_f32_16x16x32_bf16(a, b, c, 0, 0, 0)

// fold softmax scale*log2(e) into q at projection time
#define QSCALE 0.1803368801111137f   // 0.125 * 1.44269504

// counted waitcnt + raw barrier (no vmcnt(0) drain — the __syncthreads killer)
#define WAITVM(N) asm volatile("s_waitcnt vmcnt(" #N ")" ::: "memory")
#define BARRIER() asm volatile("s_barrier" ::: "memory")

#if __has_builtin(__builtin_amdgcn_exp2f)
#define EXP2F(x) __builtin_amdgcn_exp2f(x)
#else
#define EXP2F(x) exp2f(x)
#endif

__device__ __forceinline__ u16 f2bf(float f) {
    union { float f; u32 u; } x; x.f = f;
    u32 r = x.u + 0x7fffu + ((x.u >> 16) & 1u);   // RNE
    return (u16)(r >> 16);
}

// packed f32 pair -> 2x bf16 in one VALU op (RNE)
__device__ __forceinline__ u32 cvtpk(float lo, float hi) {
    u32 r;
    asm("v_cvt_pk_bf16_f32 %0, %1, %2" : "=v"(r) : "v"(lo), "v"(hi));
    return r;
}

// async global->LDS, 16B per lane; LDS dest is wave-uniform base + lane*16
__device__ __forceinline__ void stage16(const u16* g, u16* l) {
    __builtin_amdgcn_global_load_lds(
        (const __attribute__((address_space(1))) void*)g,
        (__attribute__((address_space(3))) void*)l, 16, 0, 0);
}

// ---------------------------------------------------------------------------
// Weight transposes:
//   z=0: w_proj [256][768] -> wpT [768][256]
//   z=1: w_out  [256][256] -> woT [256][256]
// ---------------------------------------------------------------------------
__global__ __launch_bounds__(256) void transpose_w(
    const float* __restrict__ wp, u16* __restrict__ wpT,
    const float* __restrict__ wo, u16* __restrict__ woT)
{
    const int z = blockIdx.z;
    const int Cc = z ? 256 : 768;
    if ((int)blockIdx.x * 64 >= Cc) return;
    const float* src = z ? wo : wp;
    u16* dst = z ? woT : wpT;
    const int R = 256;

    __shared__ float T[64][65];
    const int tid = threadIdx.x;
    const int c0 = blockIdx.x * 64, r0 = blockIdx.y * 64;

    const int l64 = tid & 63, rr0 = tid >> 6;
    #pragma unroll
    for (int t = 0; t < 16; ++t) {
        int rr = rr0 + t * 4;
        T[rr][l64] = src[(size_t)(r0 + rr) * Cc + c0 + l64];
    }
    __syncthreads();
    const int rp = tid & 31;
    const int cb = tid >> 5;
    #pragma unroll
    for (int t = 0; t < 8; ++t) {
        int c = cb + t * 8;
        u32 lo = f2bf(T[2 * rp][c]);
        u32 hi = f2bf(T[2 * rp + 1][c]);
        *(u32*)&dst[(size_t)(c0 + c) * R + r0 + 2 * rp] = lo | (hi << 16);
    }
}

// ---------------------------------------------------------------------------
// FUSED QKV projection: block = one head's full panel, 128(M=s) x 192(N=n),
// K=256, BK=64, 4 phases, double-buffered (80 KB LDS = 2 blocks/CU).
// A staged from fp32 x via float4 + cvt_pk into rotated LDS layout.
// K and V written FRAGMENT-PACKED [bh][tile16][frag8][lane64][8], dst-linear
// stores (1 KB contiguous per wave instruction), kappa applied on LDS read.
// ---------------------------------------------------------------------------
__global__ __launch_bounds__(256, 2) void qkv_fused(
    const float* __restrict__ x, const u16* __restrict__ wpT,
    const float* __restrict__ bp, u16* __restrict__ qo,
    u16* __restrict__ ko, u16* __restrict__ vo)
{
    // 2 x (As 8192 u16 [128s x 64k rotated] + Bs 12288 u16 [192n x 64k]) = 80 KB
    __shared__ __align__(16) u16 SM[40960];

    const int tid = threadIdx.x;
    const int w = tid >> 6, lane = tid & 63;
    const int n_ = lane & 15, quad = lane >> 4;

    // XCD-chunked 1D grid: 4 head-blocks of one (b,s0) group adjacent per XCD
    const int id  = blockIdx.x;
    const int nid = (id & 7) * 64 + (id >> 3);
    const int hd  = nid & 3;
    const int g   = nid >> 2;
    const int s0  = (g & 7) * 128;
    const int b   = g >> 3;
    const int bh  = b * NH + hd;

    // ---- A-staging role: thread = (kq8 = 8 k-columns, row4 = 4 s-rows) ----
    const int kq8  = tid >> 5;    // 0..7 -> k = kq8*8..+7 within the 64-k phase
    const int row4 = tid & 31;    // rows row4*4..+3
    const float* xb = x + ((size_t)b * C_ + kq8 * 8) * S_ + s0 + row4 * 4;

    int awaddr[4];
    {
        const int kc = kq8 >> 2, quadk = kq8 & 3;
        #pragma unroll
        for (int j = 0; j < 4; ++j) {
            int row = row4 * 4 + j;
            awaddr[j] = ((row >> 4) * 2 + kc) * 512 + quadk * 128 +
                        ((((row & 15) + (row >> 4)) & 15) * 8);
        }
    }

    // ---- B staging: wave w stages n-rowgroups w*3..w*3+2, kc 0..1 ----
    const u16* brp[3];
    #pragma unroll
    for (int i = 0; i < 3; ++i)
        brp[i] = wpT + (size_t)(hd * 192 + (w * 3 + i) * 16 + n_) * C_ + quad * 8;

    f32x4 acc[2][12];
    #pragma unroll
    for (int am = 0; am < 2; ++am)
        #pragma unroll
        for (int nf = 0; nf < 12; ++nf)
            #pragma unroll
            for (int r = 0; r < 4; ++r) acc[am][nf][r] = 0.f;

    float4 av[8];

    // ---- prologue: phase 0 into buf 0 ----
    #pragma unroll
    for (int ci = 0; ci < 8; ++ci)
        av[ci] = *(const float4*)(xb + (size_t)ci * S_);
    {
        u16* Bs0 = SM + 8192;
        #pragma unroll
        for (int i = 0; i < 3; ++i) {
            stage16(brp[i],      Bs0 + ((w * 3 + i) * 2 + 0) * 512);
            stage16(brp[i] + 32, Bs0 + ((w * 3 + i) * 2 + 1) * 512);
        }
    }
    #pragma unroll
    for (int j = 0; j < 4; ++j) {
        union { bf16x8 v; u32 u[4]; } pk;
        pk.u[0] = cvtpk(av[0][j], av[1][j]);
        pk.u[1] = cvtpk(av[2][j], av[3][j]);
        pk.u[2] = cvtpk(av[4][j], av[5][j]);
        pk.u[3] = cvtpk(av[6][j], av[7][j]);
        *(bf16x8*)&SM[awaddr[j]] = pk.v;
    }
    __syncthreads();

    // ---- main loop: 4 K-phases ----
    #pragma unroll
    for (int p = 0; p < 4; ++p) {
        u16* As_ = SM + (p & 1) * 20480;
        u16* Bs_ = As_ + 8192;
        u16* An  = SM + ((p + 1) & 1) * 20480;
        u16* Bn  = An + 8192;

        if (p < 3) {
            #pragma unroll
            for (int ci = 0; ci < 8; ++ci)
                av[ci] = *(const float4*)(xb + ((size_t)(p + 1) * 64 + ci) * S_);
            #pragma unroll
            for (int i = 0; i < 3; ++i) {
                stage16(brp[i] + (p + 1) * 64,      Bn + ((w * 3 + i) * 2 + 0) * 512);
                stage16(brp[i] + (p + 1) * 64 + 32, Bn + ((w * 3 + i) * 2 + 1) * 512);
            }
        }

        #pragma unroll
        for (int kc = 0; kc < 2; ++kc) {
            bf16x8 af0 = *(const bf16x8*)&As_[((2 * w + 0) * 2 + kc) * 512 +
                                              quad * 128 + (((n_ + 2 * w + 0) & 15) * 8)];
            bf16x8 af1 = *(const bf16x8*)&As_[((2 * w + 1) * 2 + kc) * 512 +
                                              quad * 128 + (((n_ + 2 * w + 1) & 15) * 8)];
            #pragma unroll
            for (int nf = 0; nf < 12; ++nf) {
                bf16x8 bf = *(const bf16x8*)&Bs_[(nf * 2 + kc) * 512 + lane * 8];
                acc[0][nf] = MFMA16(af0, bf, acc[0][nf]);
                acc[1][nf] = MFMA16(af1, bf, acc[1][nf]);
            }
        }

        if (p < 3) {
            #pragma unroll
            for (int j = 0; j < 4; ++j) {
                union { bf16x8 v; u32 u[4]; } pk;
                pk.u[0] = cvtpk(av[0][j], av[1][j]);
                pk.u[1] = cvtpk(av[2][j], av[3][j]);
                pk.u[2] = cvtpk(av[4][j], av[5][j]);
                pk.u[3] = cvtpk(av[6][j], av[7][j]);
                *(bf16x8*)&An[awaddr[j]] = pk.v;
            }
        }
        __syncthreads();
    }

    // ---- epilogue: q (scaled), k, v — k/v fragment-packed, dst-linear ----
    float bias[12];
    #pragma unroll
    for (int nf = 0; nf < 12; ++nf) bias[nf] = bp[hd * 192 + nf * 16 + n_];

    u16* Cq = SM;              // [128][72]
    u16* Ck = SM + 9216;       // [128][72]
    u16* Cv = SM + 18432;      // [64][136]

    #pragma unroll
    for (int am = 0; am < 2; ++am) {
        int row0 = w * 32 + am * 16 + quad * 4;
        #pragma unroll
        for (int nf = 0; nf < 4; ++nf)
            #pragma unroll
            for (int r = 0; r < 4; ++r)
                Cq[(row0 + r) * 72 + nf * 16 + n_] =
                    f2bf((acc[am][nf][r] + bias[nf]) * QSCALE);
        #pragma unroll
        for (int nf = 4; nf < 8; ++nf)
            #pragma unroll
            for (int r = 0; r < 4; ++r)
                Ck[(row0 + r) * 72 + (nf - 4) * 16 + n_] =
                    f2bf(acc[am][nf][r] + bias[nf]);
        int colb = w * 32 + am * 16 + quad * 4;
        #pragma unroll
        for (int nf = 8; nf < 12; ++nf)
            #pragma unroll
            for (int r = 0; r < 4; ++r)
                Cv[((nf - 8) * 16 + n_) * 136 + colb + r] =
                    f2bf(acc[am][nf][r] + bias[nf]);
    }
    __syncthreads();

    // q: plain [bh][s][dk]
    #pragma unroll
    for (int t = 0; t < 4; ++t) {
        int ii = tid + t * 256;
        int row = ii >> 3, c8 = (ii & 7) * 8;
        *(bf16x8*)&qo[((size_t)bh * S_ + s0 + row) * DK + c8] =
            *(const bf16x8*)&Cq[row * 72 + c8];
    }
    // k/v: dst-linear — each store instruction writes 64 lanes x 16 B = 1 KB
    // contiguous; kappa permutation applied on the LDS-read address.
    {
        const int jt0 = s0 >> 6;
        const int nk = lane & 15, qd = lane >> 4;
        #pragma unroll
        for (int fi = 0; fi < 2; ++fi) {
            const int f  = 2 * w + fi;
            const int nb = f >> 1, h = f & 1;     // k: MFMA block nb, half h
            const int rk = 32 * (nb & 1) + 8 * ((nk >> 2) & 3) +
                           4 * (nb >> 1) + (nk & 3);
            #pragma unroll
            for (int tt = 0; tt < 2; ++tt) {
                *(bf16x8*)&ko[((size_t)((bh * 16 + jt0 + tt) * 8 + f)) * 512 + lane * 8] =
                    *(const bf16x8*)&Ck[(tt * 64 + rk) * 72 + h * 32 + qd * 8];
                *(bf16x8*)&vo[((size_t)((bh * 16 + jt0 + tt) * 8 + f)) * 512 + lane * 8] =
                    *(const bf16x8*)&Cv[(nb * 16 + nk) * 136 + tt * 64 + h * 32 + qd * 8];
            }
        }
    }
}

// ---------------------------------------------------------------------------
// Flash attention: FRAGMENT-PACKED K/V staged to LDS with LINEAR stage16
// sources. NEW: TWO 64-key tiles per barrier interval, RING-5 LDS (5 x 16 KB
// = 80 KB, still 2 blocks/CU) — halves the block-wide barrier count (16->8).
// Safety: interval i reads slots {2i-1,2i,2i+1}%5, stages {2i+2,2i+3}%5 —
// disjoint mod 5; each staged slot's previous V was read in interval i-1,
// protected by barrier(i). WAITVM(0) pre-barrier is cheap (~1.5 intervals of
// load flight). T15 2-tile pipeline + ones-MFMA row-sum retained.
// ---------------------------------------------------------------------------
__global__ __launch_bounds__(256, 2) void attn_mfma(
    const u16* __restrict__ q, const u16* __restrict__ k,
    const u16* __restrict__ vt, u16* __restrict__ obf)
{
    // ring of 5 x (K 4096 u16 + V 4096 u16) = 80 KB; epilogue reuses SM
    __shared__ __align__(16) u16 SM[40960];

    const int tid = threadIdx.x;
    const int w = tid >> 6, lane = tid & 63;
    const int n_ = lane & 15, quad = lane >> 4;

    // XCD swizzle: 512 blocks, 8 XCDs, 64-block chunks (8 complete heads/XCD)
    const int id  = blockIdx.x;
    const int nid = (id & 7) * 64 + (id >> 3);
    const int i0  = (nid & 7) * 128;
    const int bh  = nid >> 3;
    const int hd  = bh & 3;
    const int b   = bh >> 2;

    // Q fragments (B-operand; scale pre-folded): query = i0 + w*32 + am*16 + n_
    bf16x8 qf[2][2];
    #pragma unroll
    for (int am = 0; am < 2; ++am) {
        const u16* qrow = q + ((size_t)bh * S_ + i0 + w * 32 + am * 16 + n_) * DK;
        qf[am][0] = *(const bf16x8*)&qrow[quad * 8];
        qf[am][1] = *(const bf16x8*)&qrow[32 + quad * 8];
    }

    // all-ones bf16 A-fragment for the row-sum MFMA (layout-independent)
    union { bf16x8 v; u32 u[4]; } ones_;
    #pragma unroll
    for (int i = 0; i < 4; ++i) ones_.u[i] = 0x3F803F80u;
    const bf16x8 onesf = ones_.v;

    // fragment-packed global bases; wave w stages frags 2w, 2w+1 of K and V.
    const u16* ksrc = k  + (size_t)bh * 16 * 4096 + (2 * w) * 512 + lane * 8;
    const u16* vsrc = vt + (size_t)bh * 16 * 4096 + (2 * w) * 512 + lane * 8;

    f32x4 oacc[2][4];
    f32x4 acc_sum[2];
    #pragma unroll
    for (int am = 0; am < 2; ++am) {
        #pragma unroll
        for (int nd = 0; nd < 4; ++nd)
            #pragma unroll
            for (int r = 0; r < 4; ++r) oacc[am][nd][r] = 0.f;
        #pragma unroll
        for (int r = 0; r < 4; ++r) acc_sum[am][r] = 0.f;
    }

    // prologue: tiles 0 and 1 into slots 0 and 1 (8 stage16/wave)
    #pragma unroll
    for (int tt = 0; tt < 2; ++tt) {
        u16* Ks = SM + tt * 8192;
        stage16(ksrc + (size_t)tt * 4096,       Ks + (2 * w + 0) * 512);
        stage16(ksrc + (size_t)tt * 4096 + 512, Ks + (2 * w + 1) * 512);
        stage16(vsrc + (size_t)tt * 4096,       Ks + 4096 + (2 * w + 0) * 512);
        stage16(vsrc + (size_t)tt * 4096 + 512, Ks + 4096 + (2 * w + 1) * 512);
    }

    bf16x8 pa[2][2];   // packed P of the PREVIOUS tile (valid for t >= 1)

    #pragma unroll
    for (int i = 0; i < 8; ++i) {
        WAITVM(0);     // loads issued >=1 interval ago — near-zero wait
        BARRIER();     // one block-wide barrier per TWO tiles
        if (i < 7) {
            // stage tiles 2i+2 -> slot (2i+2)%5 and 2i+3 -> slot (2i+3)%5
            #pragma unroll
            for (int j = 0; j < 2; ++j) {
                const int tn = 2 * i + 2 + j;
                u16* Kn = SM + (tn % 5) * 8192;
                stage16(ksrc + (size_t)tn * 4096,       Kn + (2 * w + 0) * 512);
                stage16(ksrc + (size_t)tn * 4096 + 512, Kn + (2 * w + 1) * 512);
                stage16(vsrc + (size_t)tn * 4096,       Kn + 4096 + (2 * w + 0) * 512);
                stage16(vsrc + (size_t)tn * 4096 + 512, Kn + 4096 + (2 * w + 1) * 512);
            }
        }

        #pragma unroll
        for (int j = 0; j < 2; ++j) {
            const int t = 2 * i + j;
            u16* Ks = SM + (t % 5) * 8192;
            u16* Vp = SM + (((t + 4) % 5)) * 8192 + 4096;   // V of tile t-1

            // S^T(t) = K Q^T : C rows = permuted keys, cols = queries (n_)
            f32x4 sb[2][4];
            __builtin_amdgcn_s_setprio(1);
            #pragma unroll
            for (int nb = 0; nb < 4; ++nb) {
                bf16x8 kf0 = *(const bf16x8*)&Ks[(nb * 2 + 0) * 512 + lane * 8];
                bf16x8 kf1 = *(const bf16x8*)&Ks[(nb * 2 + 1) * 512 + lane * 8];
                #pragma unroll
                for (int am = 0; am < 2; ++am) {
                    f32x4 a; a[0] = a[1] = a[2] = a[3] = 0.f;
                    a = MFMA16(kf0, qf[am][0], a);
                    a = MFMA16(kf1, qf[am][1], a);
                    sb[am][nb] = a;
                }
            }

            // PV(t-1): independent of sb(t) -> overlaps softmax below
            if (t > 0) {
                #pragma unroll
                for (int nd = 0; nd < 4; ++nd) {
                    bf16x8 vf0 = *(const bf16x8*)&Vp[(nd * 2 + 0) * 512 + lane * 8];
                    bf16x8 vf1 = *(const bf16x8*)&Vp[(nd * 2 + 1) * 512 + lane * 8];
                    #pragma unroll
                    for (int am = 0; am < 2; ++am) {
                        oacc[am][nd] = MFMA16(vf0, pa[am][0], oacc[am][nd]);
                        oacc[am][nd] = MFMA16(vf1, pa[am][1], oacc[am][nd]);
                    }
                }
                #pragma unroll
                for (int am = 0; am < 2; ++am) {
                    acc_sum[am] = MFMA16(onesf, pa[am][0], acc_sum[am]);
                    acc_sum[am] = MFMA16(onesf, pa[am][1], acc_sum[am]);
                }
            }
            __builtin_amdgcn_s_setprio(0);

            // softmax(t): exp2, packed-convert into PV B-operand layout
            #pragma unroll
            for (int am = 0; am < 2; ++am) {
                float pr[4][4];
                #pragma unroll
                for (int nb = 0; nb < 4; ++nb)
                    #pragma unroll
                    for (int r = 0; r < 4; ++r)
                        pr[nb][r] = EXP2F(sb[am][nb][r]);
                union { bf16x8 v; u32 u[4]; } p0, p1;
                p0.u[0] = cvtpk(pr[0][0], pr[0][1]);
                p0.u[1] = cvtpk(pr[0][2], pr[0][3]);
                p0.u[2] = cvtpk(pr[2][0], pr[2][1]);
                p0.u[3] = cvtpk(pr[2][2], pr[2][3]);
                p1.u[0] = cvtpk(pr[1][0], pr[1][1]);
                p1.u[1] = cvtpk(pr[1][2], pr[1][3]);
                p1.u[2] = cvtpk(pr[3][0], pr[3][1]);
                p1.u[3] = cvtpk(pr[3][2], pr[3][3]);
                pa[am][0] = p0.v;
                pa[am][1] = p1.v;
            }
        }
    }

    // drain: PV + sum for the last tile (tile 15 -> slot 15%5 = 0)
    {
        u16* Vp = SM + 0 * 8192 + 4096;
        __builtin_amdgcn_s_setprio(1);
        #pragma unroll
        for (int nd = 0; nd < 4; ++nd) {
            bf16x8 vf0 = *(const bf16x8*)&Vp[(nd * 2 + 0) * 512 + lane * 8];
            bf16x8 vf1 = *(const bf16x8*)&Vp[(nd * 2 + 1) * 512 + lane * 8];
            #pragma unroll
            for (int am = 0; am < 2; ++am) {
                oacc[am][nd] = MFMA16(vf0, pa[am][0], oacc[am][nd]);
                oacc[am][nd] = MFMA16(vf1, pa[am][1], oacc[am][nd]);
            }
        }
        #pragma unroll
        for (int am = 0; am < 2; ++am) {
            acc_sum[am] = MFMA16(onesf, pa[am][0], acc_sum[am]);
            acc_sum[am] = MFMA16(onesf, pa[am][1], acc_sum[am]);
        }
        __builtin_amdgcn_s_setprio(0);
    }

    const float inv0 = 1.f / acc_sum[0][0];
    const float inv1 = 1.f / acc_sum[1][0];
    float inv[2] = {inv0, inv1};

    // epilogue: O^T[dk=nd*16+quad*4+r][query=n_] -> eb[query-local][dk]
    __syncthreads();   // full drain once; reuse SM
    u16* eb = SM + w * 2304;   // [32][72]
    #pragma unroll
    for (int am = 0; am < 2; ++am)
        #pragma unroll
        for (int nd = 0; nd < 4; ++nd) {
            uint2 uv;
            uv.x = cvtpk(oacc[am][nd][0] * inv[am], oacc[am][nd][1] * inv[am]);
            uv.y = cvtpk(oacc[am][nd][2] * inv[am], oacc[am][nd][3] * inv[am]);
            *(uint2*)&eb[(am * 16 + n_) * 72 + nd * 16 + quad * 4] = uv;
        }
    __syncthreads();
    #pragma unroll
    for (int t = 0; t < 4; ++t) {
        int ii = lane + t * 64;
        int row = ii >> 3, c8 = (ii & 7) * 8;
        *(bf16x8*)&obf[((size_t)b * S_ + i0 + w * 32 + row) * ND + hd * DK + c8] =
            *(const bf16x8*)&eb[row * 72 + c8];
    }
}

// ---------------------------------------------------------------------------
// Out projection: A = woT (M=c=64), B = obf (N=s=128).
// BK=64, 4 phases, double-buffered prefetch; bijective XCD swizzle.
// Epilogue stages C(+bias) through LDS fp32 [64][140], then coalesced
// float4 x-read + out-write.
// ---------------------------------------------------------------------------
__global__ __launch_bounds__(256) void out_proj_mfma(
    const u16* __restrict__ obf, const u16* __restrict__ woT,
    const float* __restrict__ bo, const float* __restrict__ x,
    float* __restrict__ out)
{
    // 2 x (Bs 8192 [128 rows x 64 k] + As 4096 [64 rows x 64 k]) = 48 KB;
    // epilogue reuses SM as fp32 [64][140] (35.8 KB)
    __shared__ __align__(16) u16 SM[24576];

    const int tid = threadIdx.x;
    const int w = tid >> 6, lane = tid & 63;
    const int n_ = lane & 15, quad = lane >> 4;

    const int id  = blockIdx.x;
    const int nid = (id & 7) * 64 + (id >> 3);
    const int c0  = (nid & 3) * 64;
    const int g   = nid >> 2;
    const int s0  = (g & 7) * 128;
    const int b   = g >> 3;

    const u16* ar  = woT + (size_t)(c0 + w * 16 + n_) * ND + quad * 8;
    const u16* br0 = obf + ((size_t)b * S_ + s0 + (2 * w + 0) * 16 + n_) * ND + quad * 8;
    const u16* br1 = obf + ((size_t)b * S_ + s0 + (2 * w + 1) * 16 + n_) * ND + quad * 8;

    f32x4 acc[2][4];
    #pragma unroll
    for (int nf = 0; nf < 2; ++nf)
        #pragma unroll
        for (int mb = 0; mb < 4; ++mb)
            #pragma unroll
            for (int r = 0; r < 4; ++r) acc[nf][mb][r] = 0.f;

    // prologue: stage phase 0 into buf 0
    {
        u16* Bs_ = SM;
        u16* As_ = SM + 8192;
        stage16(br0,      Bs_ + (4 * w + 0) * 512);
        stage16(br0 + 32, Bs_ + (4 * w + 1) * 512);
        stage16(br1,      Bs_ + (4 * w + 2) * 512);
        stage16(br1 + 32, Bs_ + (4 * w + 3) * 512);
        stage16(ar,       As_ + (2 * w + 0) * 512);
        stage16(ar + 32,  As_ + (2 * w + 1) * 512);
    }

    #pragma unroll
    for (int p = 0; p < 4; ++p) {
        u16* Bs_ = SM + (p & 1) * 12288;
        u16* As_ = Bs_ + 8192;
        if (p < 3) {
            const int pk = (p + 1) * 64;
            u16* Bn = SM + ((p + 1) & 1) * 12288;
            u16* An = Bn + 8192;
            stage16(br0 + pk,      Bn + (4 * w + 0) * 512);
            stage16(br0 + pk + 32, Bn + (4 * w + 1) * 512);
            stage16(br1 + pk,      Bn + (4 * w + 2) * 512);
            stage16(br1 + pk + 32, Bn + (4 * w + 3) * 512);
            stage16(ar  + pk,      An + (2 * w + 0) * 512);
            stage16(ar  + pk + 32, An + (2 * w + 1) * 512);
            WAITVM(6);
        } else {
            WAITVM(0);
        }
        BARRIER();
        #pragma unroll
        for (int kc = 0; kc < 2; ++kc) {
            bf16x8 bf0 = *(const bf16x8*)&Bs_[((2 * w + 0) * 2 + kc) * 512 + lane * 8];
            bf16x8 bf1 = *(const bf16x8*)&Bs_[((2 * w + 1) * 2 + kc) * 512 + lane * 8];
            #pragma unroll
            for (int mb = 0; mb < 4; ++mb) {
                bf16x8 af = *(const bf16x8*)&As_[(mb * 2 + kc) * 512 + lane * 8];
                acc[0][mb] = MFMA16(af, bf0, acc[0][mb]);
                acc[1][mb] = MFMA16(af, bf1, acc[1][mb]);
            }
        }
        if (p < 3) BARRIER();
    }

    // epilogue: C(+bias) -> LDS fp32 [64][140] -> coalesced float4 out/x
    __syncthreads();           // all waves done with MFMA LDS reads
    float* Cf = (float*)SM;    // 64 x 140 fp32 = 35840 B
    #pragma unroll
    for (int mb = 0; mb < 4; ++mb)
        #pragma unroll
        for (int r = 0; r < 4; ++r) {
            int crow = mb * 16 + quad * 4 + r;
            float bias = bo[c0 + crow];
            #pragma unroll
            for (int nf = 0; nf < 2; ++nf)
                Cf[crow * 140 + w * 32 + nf * 16 + n_] = acc[nf][mb][r] + bias;
        }
    __syncthreads();
    #pragma unroll
    for (int cr = 0; cr < 8; ++cr) {
        int row = w * 16 + cr * 2 + (lane >> 5);
        int s4  = (lane & 31) * 4;
        float4 v = *(const float4*)&Cf[row * 140 + s4];
        size_t gi = ((size_t)b * C_ + c0 + row) * S_ + s0 + s4;
        float4 xv = *(const float4*)&x[gi];
        float4 o;
        o.x = v.x + xv.x; o.y = v.y + xv.y;
        o.z = v.z + xv.z; o.w = v.w + xv.w;
        *(float4*)&out[gi] = o;
    }
}

// ---------------------------------------------------------------------------
extern "C" void kernel_launch(void* const* d_in, const int* in_sizes, int n_in,
                              void* d_out, int out_size, void* d_ws, size_t ws_size,
                              hipStream_t stream) {
    const float* x  = (const float*)d_in[0];
    const float* wp = (const float*)d_in[1];
    const float* bp = (const float*)d_in[2];
    const float* wo = (const float*)d_in[3];
    const float* bo = (const float*)d_in[4];
    float* out = (float*)d_out;

    const size_t QKV_E = (size_t)B_ * NH * S_ * DK;   // 4 Mi
    u16* q   = (u16*)d_ws;
    u16* kk  = q   + QKV_E;
    u16* vtp = kk  + QKV_E;
    u16* obf = vtp + QKV_E;                            // B*S*ND
    u16* wpT = obf + (size_t)B_ * S_ * ND;             // P3*C
    u16* woT = wpT + (size_t)P3 * C_;                  // C*ND

    transpose_w  <<<dim3(12, 4, 2),  256, 0, stream>>>(wp, wpT, wo, woT);
    qkv_fused    <<<dim3(512, 1, 1), 256, 0, stream>>>(x, wpT, bp, q, kk, vtp);
    attn_mfma    <<<dim3(512, 1, 1), 256, 0, stream>>>(q, kk, vtp, obf);
    out_proj_mfma<<<dim3(512, 1, 1), 256, 0, stream>>>(obf, woT, bo, x, out);
}